// Round 5
// baseline (551.445 us; speedup 1.0000x reference)
//
#include <hip/hip_runtime.h>
#include <hip/hip_cooperative_groups.h>
#include <stdint.h>

namespace cg = cooperative_groups;

// Problem constants
#define QP 127.0f
#define HW2 50176            // 224*224
#define NPIX 1605632         // 32*224*224
#define NELEM 25690112       // 32*16*224*224
#define ABS_GRID 2048        // fallback k_absmax_wq grid
#define NRG 56               // 224/4 row-groups per image
#define NBLK_CONV 1792       // 32 n * 56 row-groups

// ---- workspace layout (bytes) ----
#define WS_WQ    256         // 576 dwords packed weights (2304 B)
#define WS_BMAX  4096        // per-block |x| maxima (<=2048 floats fits to 16K)
#define WS_PART  16384       // 1792*32 floats of per-strip stat partials (229 KB)
#define WS_XQ    (1 << 20)   // NPIX * 16B of cin-packed int8 activations
// hdr floats: hdr_f[1] = sw, hdr_f[2] = sx, hdr_f[16..31] = A, hdr_f[32..47] = B

__device__ __forceinline__ int dot4(int a, int b, int c) {
#if defined(__has_builtin) && __has_builtin(__builtin_amdgcn_sdot4)
  return __builtin_amdgcn_sdot4(a, b, c, false);
#else
  int r = c;
  r += (int)(signed char)(a)       * (int)(signed char)(b);
  r += (int)(signed char)(a >> 8)  * (int)(signed char)(b >> 8);
  r += (int)(signed char)(a >> 16) * (int)(signed char)(b >> 16);
  r += (a >> 24) * (b >> 24);
  return r;
#endif
}

// ---- strip conv core (Round-4 verified): 4 rows x 16 cout for column cx ----
__device__ __forceinline__ void conv_strip(const int4* sXs, const int4* wq4,
                                           int cx, int (&acc)[4][16]) {
  #pragma unroll 1
  for (int kw = 0; kw < 3; ++kw) {
    int4 xr[6];                                      // staged rows 0..5
    #pragma unroll
    for (int j = 0; j < 6; ++j) xr[j] = sXs[j * 226 + cx + kw];
    #pragma unroll
    for (int c = 0; c < 16; ++c) {
      #pragma unroll
      for (int kh = 0; kh < 3; ++kh) {
        int4 wv = wq4[(c * 3 + kh) * 3 + kw];        // uniform -> SGPR
        #pragma unroll
        for (int p = 0; p < 4; ++p) {
          int4 xv = xr[p + kh];
          int a = acc[p][c];
          a = dot4(xv.x, wv.x, a);
          a = dot4(xv.y, wv.y, a);
          a = dot4(xv.z, wv.z, a);
          a = dot4(xv.w, wv.w, a);
          acc[p][c] = a;
        }
      }
    }
  }
}

// ---- strip staging from xq (Round-4 verified) ----
__device__ __forceinline__ void stage_strip(const int4* __restrict__ xq,
                                            int4* sXs, int n, int r0, int tid) {
  #pragma unroll
  for (int j = 0; j < 6; ++j) {
    int g = r0 - 1 + j;
    if (tid < 224) {
      int4 v = {0, 0, 0, 0};
      if ((unsigned)g < 224u) v = xq[(n * 224 + g) * 224 + tid];
      sXs[j * 226 + 1 + tid] = v;
    } else if (tid < 226) {
      int4 z = {0, 0, 0, 0};
      sXs[j * 226 + ((tid == 224) ? 0 : 225)] = z;   // left / right pad col
    }
  }
}

// ======================= cooperative mega-kernel v2 =======================
// Phase A: grid-stride absmax(x) -> bmax[]; block 0 quantizes weights. sync.
// Phase B: reduce bmax -> sx; per strip: quantize-on-stage (verified float4
//          16-ch pack, 4px/task), interior rows -> xq, conv + exact stats
//          epilogue -> partials. sync.
// Finalize: block 0 only (verified k_finalize body). sync.
// Phase C: per strip: stage from xq, conv, BN+ReLU6 -> out.
// NOTE: NO min-waves launch bound — Round 1's (256,4) capped VGPR at 56 and
// spilled acc[4][16]; full budget keeps accumulators in registers.
__global__ __launch_bounds__(256) void k_mega(
    const float* __restrict__ x, const float* __restrict__ w,
    const float* __restrict__ gamma, const float* __restrict__ beta,
    float* __restrict__ out, char* __restrict__ ws) {
  __shared__ int4 sXs[6 * 226];                      // 21696 B; aliased below
  __shared__ float sRedS[4][16];
  __shared__ float sRedQ[4][16];
  __shared__ float sRed4[4];
  __shared__ float s_sw;

  float* hdr_f = (float*)ws;
  int* wqd = (int*)(ws + WS_WQ);
  const int4* wq4 = (const int4*)(ws + WS_WQ);
  float* bmax = (float*)(ws + WS_BMAX);
  float* partials = (float*)(ws + WS_PART);
  int4* xq = (int4*)(ws + WS_XQ);

  const int tid = threadIdx.x;
  const int G = gridDim.x;

  // ---------------- Phase A: absmax(x) + weight quant ----------------
  {
    const float4* x4 = (const float4*)x;
    float m = 0.0f;
    for (int i = blockIdx.x * 256 + tid; i < NELEM / 4; i += G * 256) {
      float4 v = x4[i];
      m = fmaxf(m, fmaxf(fmaxf(fabsf(v.x), fabsf(v.y)),
                         fmaxf(fabsf(v.z), fabsf(v.w))));
    }
    #pragma unroll
    for (int off = 32; off; off >>= 1) m = fmaxf(m, __shfl_down(m, off, 64));
    if ((tid & 63) == 0) sRed4[tid >> 6] = m;
    __syncthreads();
    if (tid == 0)
      bmax[blockIdx.x] =
          fmaxf(fmaxf(sRed4[0], sRed4[1]), fmaxf(sRed4[2], sRed4[3]));

    if (blockIdx.x == 0) {                           // weight quant (verified)
      __syncthreads();                               // sRed4 reuse
      float mw = 0.0f;
      for (int i = tid; i < 2304; i += 256) mw = fmaxf(mw, fabsf(w[i]));
      #pragma unroll
      for (int off = 32; off; off >>= 1) mw = fmaxf(mw, __shfl_down(mw, off, 64));
      if ((tid & 63) == 0) sRed4[tid >> 6] = mw;
      __syncthreads();
      if (tid == 0) {
        float sw = fmaxf(fmaxf(sRed4[0], sRed4[1]), fmaxf(sRed4[2], sRed4[3])) / QP;
        hdr_f[1] = sw;
        s_sw = sw;
      }
      __syncthreads();
      float sw = s_sw;
      // pack: wq[(cout*9 + kh*3+kw)*4 + c4], byte j of dword = cin 4*c4+j
      for (int i = tid; i < 576; i += 256) {
        int cout = i / 36; int r = i - cout * 36;
        int tap = r >> 2;  int c4 = r & 3;
        int kh = tap / 3, kw2 = tap - kh * 3;
        unsigned bits = 0;
        #pragma unroll
        for (int j = 0; j < 4; ++j) {
          int cin = c4 * 4 + j;
          float v = w[((cout * 16 + cin) * 3 + kh) * 3 + kw2];
          int q = (int)rintf(v / sw);                // rint = round-half-even
          q = max(-127, min(127, q));
          bits |= ((unsigned)(q & 0xff)) << (8 * j);
        }
        wqd[i] = (int)bits;
      }
    }
  }
  cg::this_grid().sync();

  // ---------------- Phase B: sx; quantize-on-stage + stats conv ----------------
  __syncthreads();                                   // sRed4 reuse across phases
  float m2 = 0.0f;
  for (int i = tid; i < G; i += 256) m2 = fmaxf(m2, bmax[i]);
  #pragma unroll
  for (int off = 32; off; off >>= 1) m2 = fmaxf(m2, __shfl_down(m2, off, 64));
  if ((tid & 63) == 0) sRed4[tid >> 6] = m2;
  __syncthreads();
  const float sx =
      fmaxf(fmaxf(sRed4[0], sRed4[1]), fmaxf(sRed4[2], sRed4[3])) / QP;

  for (int strip = blockIdx.x; strip < NBLK_CONV; strip += G) {
    const int n = strip / NRG, rg = strip - n * NRG;
    const int r0 = rg * 4;

    // quantize-stage: task = (row j of 6, group g of 56), 4 px each.
    // Verified float4 16-channel pack (k_quant_x body) per task.
    for (int task = tid; task < 336; task += 256) {
      int j = task / 56, g = task - j * 56;
      int gr = r0 - 1 + j;
      int4 v[4] = {{0,0,0,0}, {0,0,0,0}, {0,0,0,0}, {0,0,0,0}};
      if ((unsigned)gr < 224u) {
        const float4* xb = (const float4*)x + (size_t)n * 16 * (HW2 / 4)
                           + gr * 56 + g;
        unsigned comp[4][4];
        #pragma unroll
        for (int k = 0; k < 4; ++k)
          #pragma unroll
          for (int q4 = 0; q4 < 4; ++q4) comp[k][q4] = 0u;
        #pragma unroll
        for (int c = 0; c < 16; ++c) {
          float4 vc = xb[c * (HW2 / 4)];
          float f[4] = {vc.x, vc.y, vc.z, vc.w};
          #pragma unroll
          for (int k = 0; k < 4; ++k) {
            int q = (int)rintf(f[k] / sx);           // f32 div, matches ref
            q = max(-127, min(127, q));
            comp[k][c >> 2] |= ((unsigned)(q & 0xff)) << (8 * (c & 3));
          }
        }
        #pragma unroll
        for (int k = 0; k < 4; ++k) {
          v[k].x = (int)comp[k][0]; v[k].y = (int)comp[k][1];
          v[k].z = (int)comp[k][2]; v[k].w = (int)comp[k][3];
        }
        if (j >= 1 && j <= 4) {                      // interior row: owned here
          #pragma unroll
          for (int k = 0; k < 4; ++k)
            xq[(n * 224 + gr) * 224 + 4 * g + k] = v[k];
        }
      }
      #pragma unroll
      for (int k = 0; k < 4; ++k) sXs[j * 226 + 1 + 4 * g + k] = v[k];
    }
    if (tid >= 244) {                                // 12 pad entries (6 rows x 2)
      int idx = tid - 244;
      int4 z = {0, 0, 0, 0};
      sXs[(idx >> 1) * 226 + ((idx & 1) ? 225 : 0)] = z;
    }
    __syncthreads();

    int acc[4][16];
    #pragma unroll
    for (int p = 0; p < 4; ++p)
      #pragma unroll
      for (int c = 0; c < 16; ++c) acc[p][c] = 0;
    if (tid < 224) conv_strip(sXs, wq4, tid, acc);   // lanes 224..255 stay zero

    // ---- stats epilogue: LDS transpose (stride 257) + EXACT reduction ----
    // (Round-4 verified: bijective (row cc, col-group tid>>4) coverage.)
    float* sR = (float*)sXs;                         // 16448 B used
    int wv_ = tid >> 6, cc = tid & 15;
    const int colbase = (tid >> 4) << 4;             // tid & ~15
    __syncthreads();                                 // all sXs reads done
    #pragma unroll
    for (int c = 0; c < 16; ++c) {
      int si = acc[0][c] + acc[1][c] + acc[2][c] + acc[3][c];  // exact in int32
      sR[c * 257 + tid] = (float)si;
    }
    __syncthreads();
    {
      float ps = 0.0f;
      #pragma unroll
      for (int j = 0; j < 16; ++j) ps += sR[cc * 257 + colbase + j];
      ps += __shfl_xor(ps, 16, 64);
      ps += __shfl_xor(ps, 32, 64);
      if ((tid & 63) < 16) sRedS[wv_][cc] = ps;
    }
    __syncthreads();
    #pragma unroll
    for (int c = 0; c < 16; ++c) {
      float f0 = (float)acc[0][c], f1 = (float)acc[1][c];
      float f2 = (float)acc[2][c], f3 = (float)acc[3][c];
      sR[c * 257 + tid] = f0 * f0 + f1 * f1 + f2 * f2 + f3 * f3;
    }
    __syncthreads();
    {
      float pq = 0.0f;
      #pragma unroll
      for (int j = 0; j < 16; ++j) pq += sR[cc * 257 + colbase + j];
      pq += __shfl_xor(pq, 16, 64);
      pq += __shfl_xor(pq, 32, 64);
      if ((tid & 63) < 16) sRedQ[wv_][cc] = pq;
    }
    __syncthreads();
    if (tid < 32) {
      int c = tid & 15;
      float t;
      if (tid < 16) t = sRedS[0][c] + sRedS[1][c] + sRedS[2][c] + sRedS[3][c];
      else          t = sRedQ[0][c] + sRedQ[1][c] + sRedQ[2][c] + sRedQ[3][c];
      partials[strip * 32 + tid] = t;
    }
    __syncthreads();                                 // protect LDS for next strip
  }
  cg::this_grid().sync();

  // ---------------- Finalize: block 0 only (verified k_finalize body) ----------------
  if (blockIdx.x == 0) {
    double* sdd = (double*)sXs;                      // [256*4] = 8192 B
    double* sfin = ((double*)sXs) + 1024;            // 32 doubles (8192..8448)
    const float4* p4 = (const float4*)partials;      // 14336 float4s
    double d0 = 0, d1 = 0, d2 = 0, d3 = 0;
    #pragma unroll 8
    for (int k = 0; k < 56; ++k) {                   // 56*256*4 = 57344 floats
      float4 v = p4[tid + 256 * k];
      d0 += (double)v.x; d1 += (double)v.y; d2 += (double)v.z; d3 += (double)v.w;
    }
    // stat id of d_j is ((4*t) % 32) + j  (1024 == 0 mod 32 -> constant over k)
    sdd[tid * 4 + 0] = d0; sdd[tid * 4 + 1] = d1;
    sdd[tid * 4 + 2] = d2; sdd[tid * 4 + 3] = d3;
    __syncthreads();
    if (tid < 32) {
      double s = 0.0;
      #pragma unroll 8
      for (int i = 0; i < 32; ++i) s += sdd[((tid >> 2) + 8 * i) * 4 + (tid & 3)];
      sfin[tid] = s;
    }
    __syncthreads();
    if (tid < 16) {
      float sf = sx * hdr_f[1];                      // sx * sw (f32, verified)
      double s = (double)sf;
      const double M = (double)NPIX;
      double mean = s * sfin[tid] / M;
      double ey2 = s * s * sfin[16 + tid] / M;
      double var = ey2 - mean * mean;                // biased var, matches jnp.var
      double inv = (double)gamma[tid] / sqrt(var + 1e-5);
      hdr_f[16 + tid] = (float)(s * inv);            // A: applied to raw int acc
      hdr_f[32 + tid] = (float)((double)beta[tid] - mean * inv);  // B
    }
  }
  cg::this_grid().sync();

  // ---------------- Phase C: output conv (Round-4 verified body) ----------------
  for (int strip = blockIdx.x; strip < NBLK_CONV; strip += G) {
    const int n = strip / NRG, rg = strip - n * NRG;
    const int r0 = rg * 4;

    stage_strip(xq, sXs, n, r0, tid);
    __syncthreads();

    if (tid < 224) {
      int acc[4][16];
      #pragma unroll
      for (int p = 0; p < 4; ++p)
        #pragma unroll
        for (int c = 0; c < 16; ++c) acc[p][c] = 0;
      conv_strip(sXs, wq4, tid, acc);

      #pragma unroll
      for (int c = 0; c < 16; ++c) {
        float A = hdr_f[16 + c], B = hdr_f[32 + c];  // uniform -> SGPR
        #pragma unroll
        for (int p = 0; p < 4; ++p) {
          float y = fmaf((float)acc[p][c], A, B);
          y = fminf(fmaxf(y, 0.0f), 6.0f);
          out[((n * 16 + c) * 224 + (r0 + p)) * 224 + tid] = y;
        }
      }
    }
    __syncthreads();                                 // protect sXs for next strip
  }
}

// ======================= fallback: Round-4 verified 5-kernel path =======================
__global__ __launch_bounds__(256) void k_absmax_wq(const float* __restrict__ x,
                                                   const float* __restrict__ w,
                                                   char* __restrict__ ws) {
  __shared__ float red[4];
  __shared__ float s_sw;
  float* hdr_f = (float*)ws;
  float* bmax = (float*)(ws + WS_BMAX);
  int* wq = (int*)(ws + WS_WQ);
  const int tid = threadIdx.x;

  const float4* x4 = (const float4*)x;
  float m = 0.0f;
  for (int i = blockIdx.x * 256 + tid; i < NELEM / 4; i += ABS_GRID * 256) {
    float4 v = x4[i];
    m = fmaxf(m, fmaxf(fmaxf(fabsf(v.x), fabsf(v.y)),
                       fmaxf(fabsf(v.z), fabsf(v.w))));
  }
  #pragma unroll
  for (int off = 32; off; off >>= 1) m = fmaxf(m, __shfl_down(m, off, 64));
  if ((tid & 63) == 0) red[tid >> 6] = m;
  __syncthreads();
  if (tid == 0)
    bmax[blockIdx.x] = fmaxf(fmaxf(red[0], red[1]), fmaxf(red[2], red[3]));

  if (blockIdx.x == 0) {
    __syncthreads();
    float mw = 0.0f;
    for (int i = tid; i < 2304; i += 256) mw = fmaxf(mw, fabsf(w[i]));
    #pragma unroll
    for (int off = 32; off; off >>= 1) mw = fmaxf(mw, __shfl_down(mw, off, 64));
    if ((tid & 63) == 0) red[tid >> 6] = mw;
    __syncthreads();
    if (tid == 0) {
      float sw = fmaxf(fmaxf(red[0], red[1]), fmaxf(red[2], red[3])) / QP;
      hdr_f[1] = sw;
      s_sw = sw;
    }
    __syncthreads();
    float sw = s_sw;
    for (int i = tid; i < 576; i += 256) {
      int cout = i / 36; int r = i - cout * 36;
      int tap = r >> 2;  int c4 = r & 3;
      int kh = tap / 3, kw = tap - kh * 3;
      unsigned bits = 0;
      #pragma unroll
      for (int j = 0; j < 4; ++j) {
        int cin = c4 * 4 + j;
        float v = w[((cout * 16 + cin) * 3 + kh) * 3 + kw];
        int q = (int)rintf(v / sw);
        q = max(-127, min(127, q));
        bits |= ((unsigned)(q & 0xff)) << (8 * j);
      }
      wq[i] = (int)bits;
    }
  }
}

__global__ __launch_bounds__(256) void k_quant_x(const float* __restrict__ x,
                                                 char* __restrict__ ws) {
  __shared__ float sRed4[4];
  const float* __restrict__ bmax = (const float*)(ws + WS_BMAX);
  float* hdr_f = (float*)ws;
  int4* xq = (int4*)(ws + WS_XQ);
  const int tid = threadIdx.x;

  float m = 0.0f;
  for (int i = tid; i < ABS_GRID; i += 256) m = fmaxf(m, bmax[i]);
  #pragma unroll
  for (int off = 32; off; off >>= 1) m = fmaxf(m, __shfl_down(m, off, 64));
  if ((tid & 63) == 0) sRed4[tid >> 6] = m;
  __syncthreads();
  const float sx =
      fmaxf(fmaxf(sRed4[0], sRed4[1]), fmaxf(sRed4[2], sRed4[3])) / QP;
  if (blockIdx.x == 0 && tid == 0) hdr_f[2] = sx;

  int t = blockIdx.x * 256 + tid;
  int p0 = t * 4;
  int n = p0 / HW2;
  int hw = p0 - n * HW2;
  const float4* xb = (const float4*)(x + (size_t)n * 16 * HW2 + hw);
  unsigned comp[4][4];
  #pragma unroll
  for (int j = 0; j < 4; ++j)
    #pragma unroll
    for (int k = 0; k < 4; ++k) comp[j][k] = 0u;
  #pragma unroll
  for (int c = 0; c < 16; ++c) {
    float4 vc = xb[c * (HW2 / 4)];
    float f[4] = {vc.x, vc.y, vc.z, vc.w};
    #pragma unroll
    for (int j = 0; j < 4; ++j) {
      int q = (int)rintf(f[j] / sx);
      q = max(-127, min(127, q));
      comp[j][c >> 2] |= ((unsigned)(q & 0xff)) << (8 * (c & 3));
    }
  }
  #pragma unroll
  for (int j = 0; j < 4; ++j) {
    int4 v;
    v.x = (int)comp[j][0]; v.y = (int)comp[j][1];
    v.z = (int)comp[j][2]; v.w = (int)comp[j][3];
    xq[p0 + j] = v;
  }
}

__global__ __launch_bounds__(256) void k_conv_stats(const char* __restrict__ ws,
                                                    float* __restrict__ partials) {
  __shared__ int4 sXs[6 * 226];
  __shared__ float sRedS[4][16];
  __shared__ float sRedQ[4][16];
  const int4* __restrict__ xq = (const int4*)(ws + WS_XQ);
  const int4* __restrict__ wq4 = (const int4*)(ws + WS_WQ);

  const int tid = threadIdx.x;
  const int b = blockIdx.x;
  const int n = b / NRG, rg = b - n * NRG;
  const int r0 = rg * 4;

  stage_strip(xq, sXs, n, r0, tid);
  __syncthreads();

  int acc[4][16];
  #pragma unroll
  for (int p = 0; p < 4; ++p)
    #pragma unroll
    for (int c = 0; c < 16; ++c) acc[p][c] = 0;
  if (tid < 224) conv_strip(sXs, wq4, tid, acc);

  float* sR = (float*)sXs;
  int wv_ = tid >> 6, cc = tid & 15;
  const int colbase = (tid >> 4) << 4;
  __syncthreads();
  #pragma unroll
  for (int c = 0; c < 16; ++c) {
    int si = acc[0][c] + acc[1][c] + acc[2][c] + acc[3][c];
    sR[c * 257 + tid] = (float)si;
  }
  __syncthreads();
  {
    float ps = 0.0f;
    #pragma unroll
    for (int j = 0; j < 16; ++j) ps += sR[cc * 257 + colbase + j];
    ps += __shfl_xor(ps, 16, 64);
    ps += __shfl_xor(ps, 32, 64);
    if ((tid & 63) < 16) sRedS[wv_][cc] = ps;
  }
  __syncthreads();
  #pragma unroll
  for (int c = 0; c < 16; ++c) {
    float f0 = (float)acc[0][c], f1 = (float)acc[1][c];
    float f2 = (float)acc[2][c], f3 = (float)acc[3][c];
    sR[c * 257 + tid] = f0 * f0 + f1 * f1 + f2 * f2 + f3 * f3;
  }
  __syncthreads();
  {
    float pq = 0.0f;
    #pragma unroll
    for (int j = 0; j < 16; ++j) pq += sR[cc * 257 + colbase + j];
    pq += __shfl_xor(pq, 16, 64);
    pq += __shfl_xor(pq, 32, 64);
    if ((tid & 63) < 16) sRedQ[wv_][cc] = pq;
  }
  __syncthreads();
  if (tid < 32) {
    int c = tid & 15;
    float t;
    if (tid < 16) t = sRedS[0][c] + sRedS[1][c] + sRedS[2][c] + sRedS[3][c];
    else          t = sRedQ[0][c] + sRedQ[1][c] + sRedQ[2][c] + sRedQ[3][c];
    partials[b * 32 + tid] = t;
  }
}

__global__ void k_finalize(const float* __restrict__ partials,
                           const float* __restrict__ gamma,
                           const float* __restrict__ beta,
                           float* __restrict__ hdr_f) {
  __shared__ double sdd[256][4];
  __shared__ double sfin[32];
  int t = threadIdx.x;
  const float4* p4 = (const float4*)partials;
  double d0 = 0, d1 = 0, d2 = 0, d3 = 0;
  #pragma unroll 8
  for (int k = 0; k < 56; ++k) {
    float4 v = p4[t + 256 * k];
    d0 += (double)v.x; d1 += (double)v.y; d2 += (double)v.z; d3 += (double)v.w;
  }
  sdd[t][0] = d0; sdd[t][1] = d1; sdd[t][2] = d2; sdd[t][3] = d3;
  __syncthreads();
  if (t < 32) {
    double s = 0.0;
    #pragma unroll 8
    for (int i = 0; i < 32; ++i) s += sdd[(t >> 2) + 8 * i][t & 3];
    sfin[t] = s;
  }
  __syncthreads();
  if (t < 16) {
    float sf = hdr_f[2] * hdr_f[1];
    double s = (double)sf;
    const double M = (double)NPIX;
    double mean = s * sfin[t] / M;
    double ey2 = s * s * sfin[16 + t] / M;
    double var = ey2 - mean * mean;
    double inv = (double)gamma[t] / sqrt(var + 1e-5);
    hdr_f[16 + t] = (float)(s * inv);
    hdr_f[32 + t] = (float)((double)beta[t] - mean * inv);
  }
}

__global__ __launch_bounds__(256) void k_conv_out(const char* __restrict__ ws,
                                                  float* __restrict__ out) {
  __shared__ int4 sXs[6 * 226];
  const int4* __restrict__ xq = (const int4*)(ws + WS_XQ);
  const int4* __restrict__ wq4 = (const int4*)(ws + WS_WQ);
  const float* hdr_f = (const float*)ws;

  const int tid = threadIdx.x;
  const int b = blockIdx.x;
  const int n = b / NRG, rg = b - n * NRG;
  const int r0 = rg * 4;

  stage_strip(xq, sXs, n, r0, tid);
  __syncthreads();

  if (tid < 224) {
    int acc[4][16];
    #pragma unroll
    for (int p = 0; p < 4; ++p)
      #pragma unroll
      for (int c = 0; c < 16; ++c) acc[p][c] = 0;
    conv_strip(sXs, wq4, tid, acc);

    #pragma unroll
    for (int c = 0; c < 16; ++c) {
      float A = hdr_f[16 + c], B = hdr_f[32 + c];
      #pragma unroll
      for (int p = 0; p < 4; ++p) {
        float y = fmaf((float)acc[p][c], A, B);
        y = fminf(fmaxf(y, 0.0f), 6.0f);
        out[((n * 16 + c) * 224 + (r0 + p)) * 224 + tid] = y;
      }
    }
  }
}

extern "C" void kernel_launch(void* const* d_in, const int* in_sizes, int n_in,
                              void* d_out, int out_size, void* d_ws, size_t ws_size,
                              hipStream_t stream) {
  const float* x = (const float*)d_in[0];
  const float* w = (const float*)d_in[1];
  const float* gamma = (const float*)d_in[2];
  const float* beta = (const float*)d_in[3];
  float* out = (float*)d_out;
  char* ws = (char*)d_ws;
  float* partials = (float*)(ws + WS_PART);

  // Cooperative grid: occ blocks/CU * 256 CUs, capped at NBLK_CONV (<=2048
  // so bmax fits). 0 = unknown, -1 = permanent fallback.
  static int s_grid = 0;
  if (s_grid == 0) {
    int occ = 0;
    hipError_t e = hipOccupancyMaxActiveBlocksPerMultiprocessor(&occ, k_mega, 256, 0);
    if (e != hipSuccess || occ < 1) {
      s_grid = -1;
      (void)hipGetLastError();
    } else {
      int g = occ * 256;                             // MI355X: 256 CUs
      if (g > NBLK_CONV) g = NBLK_CONV;
      s_grid = g;
    }
  }

  bool done = false;
  if (s_grid > 0) {
    void* args[] = {(void*)&x, (void*)&w, (void*)&gamma, (void*)&beta,
                    (void*)&out, (void*)&ws};
    hipError_t e = hipLaunchCooperativeKernel(k_mega, dim3(s_grid), dim3(256),
                                              args, 0u, stream);
    if (e == hipSuccess) {
      done = true;
    } else {
      s_grid = -1;
      (void)hipGetLastError();                       // clear sticky error
    }
  }

  if (!done) {
    k_absmax_wq<<<ABS_GRID, 256, 0, stream>>>(x, w, ws);
    k_quant_x<<<1568, 256, 0, stream>>>(x, ws);
    k_conv_stats<<<NBLK_CONV, 256, 0, stream>>>(ws, partials);
    k_finalize<<<1, 256, 0, stream>>>(partials, gamma, beta, (float*)ws);
    k_conv_out<<<NBLK_CONV, 256, 0, stream>>>(ws, out);
  }
}

// Round 6
// 239.513 us; speedup vs baseline: 2.3024x; 2.3024x over previous
//
#include <hip/hip_runtime.h>
#include <stdint.h>

// Problem constants
#define QP 127.0f
#define HW2 50176            // 224*224
#define NPIX 1605632         // 32*224*224
#define NELEM 25690112       // 32*16*224*224
#define ABS_GRID 2048        // k_absmax_wq grid (bmax sized for it)
#define NRG 56               // 224/4 row-groups per image
#define NBLK_CONV 1792       // 32 n * 56 row-groups

// ---- workspace layout (bytes) ----
#define WS_WQ    256         // 576 dwords packed weights (2304 B)
#define WS_BMAX  4096        // ABS_GRID floats of per-block |x| maxima (8 KB)
#define WS_PART  16384       // 1792*32 floats of per-block stat partials (229 KB)
#define WS_XQ    (1 << 20)   // NPIX * 16B of cin-packed int8 activations
// hdr floats: hdr_f[1] = sw, hdr_f[2] = sx, hdr_f[16..31] = A, hdr_f[32..47] = B

typedef int v4i __attribute__((ext_vector_type(4)));

// ---- strip staging: 6 full-width xq rows, coalesced; zero row/col pads ----
// (Round-4 verified.)
__device__ __forceinline__ void stage_strip(const int4* __restrict__ xq,
                                            int4* sXs, int n, int r0, int tid) {
  #pragma unroll
  for (int j = 0; j < 6; ++j) {
    int g = r0 - 1 + j;
    if (tid < 224) {
      int4 v = {0, 0, 0, 0};
      if ((unsigned)g < 224u) v = xq[(n * 224 + g) * 224 + tid];
      sXs[j * 226 + 1 + tid] = v;
    } else if (tid < 226) {
      int4 z = {0, 0, 0, 0};
      sXs[j * 226 + ((tid == 224) ? 0 : 225)] = z;   // left / right pad col
    }
  }
}

// ---- MFMA conv geometry ----
// Implicit GEMM per strip: M = 896 px (56 tiles of 16 consecutive cols of one
// output row), N = 16 cout, K = 144 (tap*16 + cin) zero-padded to 192 = 3x64.
// A-fragment (lane row = lane&15 = px col-in-tile, chunk = lane>>4): 16 bytes =
// the cin-packed xq int4 of pixel (y+kh-1, x0+row+kw-1) for tap 4m+chunk —
// one ds_read_b128, no im2col. B-fragment: wq4[cout*9 + tap] with cout=lane&15;
// taps 9..11 are ZERO (nullifies the clamped A reads). D (m89-verified layout):
// cout = lane&15, px = (lane>>4)*4 + reg.
__device__ __forceinline__ void conv_lane_setup(const int4* __restrict__ wq4,
                                                int ccol, int chunk,
                                                v4i (&bfrag)[3], int (&abase)[3]) {
  #pragma unroll
  for (int m = 0; m < 3; ++m) {
    int tap = 4 * m + chunk;
    v4i bv = {0, 0, 0, 0};
    if (tap <= 8) {
      int4 t = wq4[ccol * 9 + tap];
      bv[0] = t.x; bv[1] = t.y; bv[2] = t.z; bv[3] = t.w;
    }
    bfrag[m] = bv;
    int tc = (tap > 8) ? 8 : tap;                    // clamp: B=0 kills it
    int kh = tc / 3, kw = tc - kh * 3;
    abase[m] = kh * 226 + ccol + kw;                 // add ty*226 + x0 at use
  }
}

// ---------------- D1: absmax(x) per block + weight quant in block 0 ----------------
// (Round-4 verified.)
__global__ __launch_bounds__(256) void k_absmax_wq(const float* __restrict__ x,
                                                   const float* __restrict__ w,
                                                   char* __restrict__ ws) {
  __shared__ float red[4];
  __shared__ float s_sw;
  float* hdr_f = (float*)ws;
  float* bmax = (float*)(ws + WS_BMAX);
  int* wq = (int*)(ws + WS_WQ);
  const int tid = threadIdx.x;

  const float4* x4 = (const float4*)x;
  float m = 0.0f;
  for (int i = blockIdx.x * 256 + tid; i < NELEM / 4; i += ABS_GRID * 256) {
    float4 v = x4[i];
    m = fmaxf(m, fmaxf(fmaxf(fabsf(v.x), fabsf(v.y)),
                       fmaxf(fabsf(v.z), fabsf(v.w))));
  }
  #pragma unroll
  for (int off = 32; off; off >>= 1) m = fmaxf(m, __shfl_down(m, off, 64));
  if ((tid & 63) == 0) red[tid >> 6] = m;
  __syncthreads();
  if (tid == 0)
    bmax[blockIdx.x] = fmaxf(fmaxf(red[0], red[1]), fmaxf(red[2], red[3]));

  if (blockIdx.x == 0) {                             // weight quant (verified)
    __syncthreads();                                 // red[] reuse
    float mw = 0.0f;
    for (int i = tid; i < 2304; i += 256) mw = fmaxf(mw, fabsf(w[i]));
    #pragma unroll
    for (int off = 32; off; off >>= 1) mw = fmaxf(mw, __shfl_down(mw, off, 64));
    if ((tid & 63) == 0) red[tid >> 6] = mw;
    __syncthreads();
    if (tid == 0) {
      float sw = fmaxf(fmaxf(red[0], red[1]), fmaxf(red[2], red[3])) / QP;
      hdr_f[1] = sw;
      s_sw = sw;
    }
    __syncthreads();
    float sw = s_sw;
    // pack: wq[(cout*9 + kh*3+kw)*4 + c4], byte j of dword = cin 4*c4+j
    for (int i = tid; i < 576; i += 256) {
      int cout = i / 36; int r = i - cout * 36;
      int tap = r >> 2;  int c4 = r & 3;
      int kh = tap / 3, kw = tap - kh * 3;
      unsigned bits = 0;
      #pragma unroll
      for (int j = 0; j < 4; ++j) {
        int cin = c4 * 4 + j;
        float v = w[((cout * 16 + cin) * 3 + kh) * 3 + kw];
        int q = (int)rintf(v / sw);                  // rint = round-half-even
        q = max(-127, min(127, q));
        bits |= ((unsigned)(q & 0xff)) << (8 * j);
      }
      wq[i] = (int)bits;
    }
  }
}

// ---------------- D2: quantize x -> NHWC cin-packed int8 (streaming) ----------------
// (Round-4 verified.)
__global__ __launch_bounds__(256) void k_quant_x(const float* __restrict__ x,
                                                 char* __restrict__ ws) {
  __shared__ float sRed4[4];
  const float* __restrict__ bmax = (const float*)(ws + WS_BMAX);
  float* hdr_f = (float*)ws;
  int4* xq = (int4*)(ws + WS_XQ);
  const int tid = threadIdx.x;

  float m = 0.0f;
  for (int i = tid; i < ABS_GRID; i += 256) m = fmaxf(m, bmax[i]);
  #pragma unroll
  for (int off = 32; off; off >>= 1) m = fmaxf(m, __shfl_down(m, off, 64));
  if ((tid & 63) == 0) sRed4[tid >> 6] = m;
  __syncthreads();
  const float sx =
      fmaxf(fmaxf(sRed4[0], sRed4[1]), fmaxf(sRed4[2], sRed4[3])) / QP;
  if (blockIdx.x == 0 && tid == 0) hdr_f[2] = sx;    // for k_finalize

  int t = blockIdx.x * 256 + tid;                    // grid 1568*256 = NPIX/4
  int p0 = t * 4;
  int n = p0 / HW2;                                  // HW2 % 4 == 0: no n-crossing
  int hw = p0 - n * HW2;
  const float4* xb = (const float4*)(x + (size_t)n * 16 * HW2 + hw);
  unsigned comp[4][4];
  #pragma unroll
  for (int j = 0; j < 4; ++j)
    #pragma unroll
    for (int k = 0; k < 4; ++k) comp[j][k] = 0u;
  #pragma unroll
  for (int c = 0; c < 16; ++c) {
    float4 vc = xb[c * (HW2 / 4)];
    float f[4] = {vc.x, vc.y, vc.z, vc.w};
    #pragma unroll
    for (int j = 0; j < 4; ++j) {
      int q = (int)rintf(f[j] / sx);                 // f32 div, matches ref
      q = max(-127, min(127, q));
      comp[j][c >> 2] |= ((unsigned)(q & 0xff)) << (8 * (c & 3));
    }
  }
  #pragma unroll
  for (int j = 0; j < 4; ++j) {
    int4 v;
    v.x = (int)comp[j][0]; v.y = (int)comp[j][1];
    v.z = (int)comp[j][2]; v.w = (int)comp[j][3];
    xq[p0 + j] = v;
  }
}

// ---------------- D3: MFMA strip conv, stats pass ----------------
__global__ __launch_bounds__(256) void k_conv_stats(const char* __restrict__ ws,
                                                    float* __restrict__ partials) {
  __shared__ int4 sXs[6 * 226];                      // 21696 B
  __shared__ int   sS[4][16];
  __shared__ float sQ[4][16];
  const int4* __restrict__ xq = (const int4*)(ws + WS_XQ);
  const int4* __restrict__ wq4 = (const int4*)(ws + WS_WQ);

  const int tid = threadIdx.x;
  const int b = blockIdx.x;
  const int n = b / NRG, rg = b - n * NRG;
  const int r0 = rg * 4;

  stage_strip(xq, sXs, n, r0, tid);

  const int lane = tid & 63, wid = tid >> 6;
  const int ccol = lane & 15, chunk = lane >> 4;
  v4i bfrag[3];
  int abase[3];
  conv_lane_setup(wq4, ccol, chunk, bfrag, abase);
  __syncthreads();

  int   sAcc = 0;                                    // exact int row-sums
  float qAcc = 0.0f;                                 // f32 sum of squares
  for (int t = wid; t < 56; t += 4) {                // 14 tiles per wave
    int ty = t / 14, x0 = (t - ty * 14) << 4;
    int off = ty * 226 + x0;
    v4i acc = {0, 0, 0, 0};
    #pragma unroll
    for (int m = 0; m < 3; ++m) {
      int4 av = sXs[off + abase[m]];
      v4i a; a[0] = av.x; a[1] = av.y; a[2] = av.z; a[3] = av.w;
      acc = __builtin_amdgcn_mfma_i32_16x16x64_i8(a, bfrag[m], acc, 0, 0, 0);
    }
    #pragma unroll
    for (int r = 0; r < 4; ++r) {
      int d = acc[r];                                // exact conv integer
      sAcc += d;
      float f = (float)d;
      qAcc += f * f;
    }
  }
  // reduce over the 4 chunk-groups (same cout) within the wave
  sAcc += __shfl_xor(sAcc, 16, 64);
  sAcc += __shfl_xor(sAcc, 32, 64);
  qAcc += __shfl_xor(qAcc, 16, 64);
  qAcc += __shfl_xor(qAcc, 32, 64);
  if (lane < 16) { sS[wid][ccol] = sAcc; sQ[wid][ccol] = qAcc; }
  __syncthreads();
  if (tid < 32) {
    int c = tid & 15;
    float t;
    if (tid < 16) t = (float)(sS[0][c] + sS[1][c] + sS[2][c] + sS[3][c]);
    else          t = sQ[0][c] + sQ[1][c] + sQ[2][c] + sQ[3][c];
    partials[b * 32 + tid] = t;
  }
}

// ---------------- D4: finalize BN coefficients (Round-4 verified) ----------------
__global__ void k_finalize(const float* __restrict__ partials,
                           const float* __restrict__ gamma,
                           const float* __restrict__ beta,
                           float* __restrict__ hdr_f) {
  __shared__ double sdd[256][4];
  __shared__ double sfin[32];
  int t = threadIdx.x;
  const float4* p4 = (const float4*)partials;        // 14336 float4s
  double d0 = 0, d1 = 0, d2 = 0, d3 = 0;
  #pragma unroll 8
  for (int k = 0; k < 56; ++k) {                     // 56*256*4 = 57344 floats
    float4 v = p4[t + 256 * k];
    d0 += (double)v.x; d1 += (double)v.y; d2 += (double)v.z; d3 += (double)v.w;
  }
  sdd[t][0] = d0; sdd[t][1] = d1; sdd[t][2] = d2; sdd[t][3] = d3;
  __syncthreads();
  if (t < 32) {
    double s = 0.0;
    #pragma unroll 8
    for (int i = 0; i < 32; ++i) s += sdd[(t >> 2) + 8 * i][t & 3];
    sfin[t] = s;
  }
  __syncthreads();
  if (t < 16) {
    float sf = hdr_f[2] * hdr_f[1];                  // sx * sw (f32, verified)
    double s = (double)sf;
    const double M = (double)NPIX;
    double mean = s * sfin[t] / M;
    double ey2 = s * s * sfin[16 + t] / M;
    double var = ey2 - mean * mean;                  // biased var, matches jnp.var
    double inv = (double)gamma[t] / sqrt(var + 1e-5);
    hdr_f[16 + t] = (float)(s * inv);                // A: applied to raw int acc
    hdr_f[32 + t] = (float)((double)beta[t] - mean * inv);  // B
  }
}

// ---------------- D5: MFMA strip conv, output pass ----------------
__global__ __launch_bounds__(256) void k_conv_out(const char* __restrict__ ws,
                                                  float* __restrict__ out) {
  __shared__ int4 sXs[6 * 226];
  const int4* __restrict__ xq = (const int4*)(ws + WS_XQ);
  const int4* __restrict__ wq4 = (const int4*)(ws + WS_WQ);
  const float* hdr_f = (const float*)ws;

  const int tid = threadIdx.x;
  const int b = blockIdx.x;
  const int n = b / NRG, rg = b - n * NRG;
  const int r0 = rg * 4;

  stage_strip(xq, sXs, n, r0, tid);

  const int lane = tid & 63, wid = tid >> 6;
  const int ccol = lane & 15, chunk = lane >> 4;
  v4i bfrag[3];
  int abase[3];
  conv_lane_setup(wq4, ccol, chunk, bfrag, abase);
  const float Af = hdr_f[16 + ccol];                 // BN scale for this cout
  const float Bf = hdr_f[32 + ccol];                 // BN shift
  __syncthreads();

  float* oplane = out + ((size_t)n * 16 + ccol) * HW2;
  for (int t = wid; t < 56; t += 4) {
    int ty = t / 14, x0 = (t - ty * 14) << 4;
    int off = ty * 226 + x0;
    v4i acc = {0, 0, 0, 0};
    #pragma unroll
    for (int m = 0; m < 3; ++m) {
      int4 av = sXs[off + abase[m]];
      v4i a; a[0] = av.x; a[1] = av.y; a[2] = av.z; a[3] = av.w;
      acc = __builtin_amdgcn_mfma_i32_16x16x64_i8(a, bfrag[m], acc, 0, 0, 0);
    }
    // D: px = chunk*4 + r (cols x0+chunk*4 .. +3 of output row r0+ty)
    float4 o;
    float v0 = fminf(fmaxf(fmaf((float)acc[0], Af, Bf), 0.0f), 6.0f);
    float v1 = fminf(fmaxf(fmaf((float)acc[1], Af, Bf), 0.0f), 6.0f);
    float v2 = fminf(fmaxf(fmaf((float)acc[2], Af, Bf), 0.0f), 6.0f);
    float v3 = fminf(fmaxf(fmaf((float)acc[3], Af, Bf), 0.0f), 6.0f);
    o.x = v0; o.y = v1; o.z = v2; o.w = v3;
    int y = r0 + ty, xb = x0 + chunk * 4;            // xb % 4 == 0: aligned
    *(float4*)&oplane[y * 224 + xb] = o;
  }
}

extern "C" void kernel_launch(void* const* d_in, const int* in_sizes, int n_in,
                              void* d_out, int out_size, void* d_ws, size_t ws_size,
                              hipStream_t stream) {
  const float* x = (const float*)d_in[0];
  const float* w = (const float*)d_in[1];
  const float* gamma = (const float*)d_in[2];
  const float* beta = (const float*)d_in[3];
  float* out = (float*)d_out;
  char* ws = (char*)d_ws;
  float* partials = (float*)(ws + WS_PART);

  k_absmax_wq<<<ABS_GRID, 256, 0, stream>>>(x, w, ws);
  k_quant_x<<<1568, 256, 0, stream>>>(x, ws);
  k_conv_stats<<<NBLK_CONV, 256, 0, stream>>>(ws, partials);
  k_finalize<<<1, 256, 0, stream>>>(partials, gamma, beta, (float*)ws);
  k_conv_out<<<NBLK_CONV, 256, 0, stream>>>(ws, out);
}